// Round 14
// baseline (318.014 us; speedup 1.0000x reference)
//
#include <hip/hip_runtime.h>
#include <hip/hip_cooperative_groups.h>

namespace cg = cooperative_groups;

// ---------------------------------------------------------------------------
// GraphConv (DGL norm='both') + residual linear:
//   out = (D_dst^-1/2 * A^T * (D_src^-1/2 * x)) @ W + x @ Wr + (b + br)
// Round 14: whole CSR build (hist -> partial -> scan -> scatter ->
// csr||outdeg+prescale) fused into ONE cooperative kernel with grid.sync();
// 3 launches total. fp16 xs + ushort col from R13. Zero global atomics.
// ---------------------------------------------------------------------------

#define TILE 2048   // edges per bucket block (392-block coop grid stays busy)

typedef __attribute__((ext_vector_type(4))) _Float16 half4;

__global__ __launch_bounds__(256) void build_kernel(
    const int* __restrict__ src, const int* __restrict__ dst,
    int* __restrict__ H, int* __restrict__ part, int* __restrict__ Hoff,
    int* __restrict__ packed, unsigned char* __restrict__ ksrc2,
    int* __restrict__ roff, unsigned short* __restrict__ col,
    const float4* __restrict__ x4, half4* __restrict__ xsh,
    int n, int e, int nb, int nbs, int nrange) {
    cg::grid_group grid = cg::this_grid();
    __shared__ int A[256], B[256];
    int t = threadIdx.x, blk = blockIdx.x;
    const int m = 2 * 256 * nb;

    // ---- Phase 1: per-tile LDS histograms of dst>>8 / src>>8 ----
    if (blk < nb) {
        A[t] = 0; B[t] = 0;
        __syncthreads();
        int base = blk * TILE;
        #pragma unroll
        for (int s = 0; s < 8; ++s) {
            int j = base + s * 256 + t;
            if (j < e) {
                atomicAdd(&A[dst[j] >> 8], 1);
                atomicAdd(&B[src[j] >> 8], 1);
            }
        }
        __syncthreads();
        H[t * nb + blk]            = A[t];
        H[256 * nb + t * nb + blk] = B[t];
    }
    grid.sync();

    // ---- Phase 2: 4096-elem partial sums of H ----
    if (blk < nbs) {
        int base = blk * 4096 + t * 16;
        int s = 0;
        if (base + 16 <= m) {
            const int4* p4 = (const int4*)(H + base);
            #pragma unroll
            for (int k = 0; k < 4; ++k) { int4 v = p4[k]; s += v.x + v.y + v.z + v.w; }
        } else {
            for (int k = 0; k < 16; ++k) if (base + k < m) s += H[base + k];
        }
        A[t] = s;
        __syncthreads();
        for (int st = 128; st > 0; st >>= 1) {
            if (t < st) A[t] += A[t + st];
            __syncthreads();
        }
        if (t == 0) part[blk] = A[0];
    }
    grid.sync();

    // ---- Phase 3: exclusive scan (self-scan partials + local scan) ----
    if (blk < nbs) {
        int pv = (t < nbs) ? part[t] : 0;
        B[t] = pv;
        __syncthreads();
        for (int d = 1; d < 256; d <<= 1) {
            int add = (t >= d) ? B[t - d] : 0;
            __syncthreads();
            B[t] += add;
            __syncthreads();
        }
        int ex = B[t] - pv;
        __syncthreads();
        B[t] = ex;
        __syncthreads();
        int blkoff = B[blk];

        int base = blk * 4096 + t * 16;
        int v[16];
        #pragma unroll
        for (int k = 0; k < 16; ++k) v[k] = (base + k < m) ? H[base + k] : 0;
        int s = 0;
        #pragma unroll
        for (int k = 0; k < 16; ++k) { int x = v[k]; v[k] = s; s += x; }
        A[t] = s;
        __syncthreads();
        for (int d = 1; d < 256; d <<= 1) {
            int add = (t >= d) ? A[t - d] : 0;
            __syncthreads();
            A[t] += add;
            __syncthreads();
        }
        int tb = A[t] - s + blkoff;
        #pragma unroll
        for (int k = 0; k < 16; ++k)
            if (base + k < m) Hoff[base + k] = v[k] + tb;
    }
    grid.sync();

    // ---- Phase 4: scatter into range buckets (LDS cursors) ----
    if (blk < nb) {
        A[t] = Hoff[t * nb + blk];
        B[t] = Hoff[256 * nb + t * nb + blk] - e;   // src offsets live in [e,2e)
        __syncthreads();
        int base = blk * TILE;
        #pragma unroll
        for (int s2 = 0; s2 < 8; ++s2) {
            int j = base + s2 * 256 + t;
            if (j < e) {
                int d = dst[j], sv = src[j];
                int pd = atomicAdd(&A[d >> 8], 1);
                packed[pd] = (sv << 8) | (d & 255);
                int ps = atomicAdd(&B[sv >> 8], 1);
                ksrc2[ps] = (unsigned char)(sv & 255);
            }
        }
    }
    grid.sync();

    // ---- Phase 5: CSR build (blk<nrange) || outdeg+fp16 prescale ----
    if (blk < nrange) {
        int r = blk;
        int beg = Hoff[r * nb];
        int end = (r + 1 < nrange) ? Hoff[(r + 1) * nb] : e;
        A[t] = 0;
        __syncthreads();
        for (int j = beg + t; j < end; j += 256)
            atomicAdd(&A[packed[j] & 255], 1);
        __syncthreads();
        int v0 = A[t];
        B[t] = v0;
        __syncthreads();
        for (int d = 1; d < 256; d <<= 1) {
            int add = (t >= d) ? B[t - d] : 0;
            __syncthreads();
            B[t] += add;
            __syncthreads();
        }
        int excl = B[t] - v0;
        int v = r * 256 + t;
        if (v < n) roff[v] = beg + excl;
        __syncthreads();          // all v0 reads done before A reuse
        A[t] = excl;              // A becomes the local cursor array
        __syncthreads();
        for (int j = beg + t; j < end; j += 256) {
            int p = packed[j];
            int pos = beg + atomicAdd(&A[p & 255], 1);
            col[pos] = (unsigned short)(p >> 8);
        }
        if (r == 0 && t == 0) roff[n] = e;
    } else if (blk < 2 * nrange) {
        int r = blk - nrange;
        A[t] = 0;
        __syncthreads();
        int beg = Hoff[256 * nb + r * nb] - e;
        int end = (r + 1 < nrange) ? (Hoff[256 * nb + (r + 1) * nb] - e) : e;
        for (int j = beg + t; j < end; j += 256)
            atomicAdd(&A[ksrc2[j]], 1);
        __syncthreads();
        int base = r * 256;
        for (int i = t; i < 256 * 16; i += 256) {
            int row = i >> 4, g = base + row;
            if (g < n) {
                float s = rsqrtf((float)max(A[row], 1));
                float4 v = x4[(long)g * 16 + (i & 15)];
                half4 h;
                h.x = (_Float16)(v.x * s);
                h.y = (_Float16)(v.y * s);
                h.z = (_Float16)(v.z * s);
                h.w = (_Float16)(v.w * s);
                xsh[(long)g * 16 + (i & 15)] = h;
            }
        }
    }
}

// One wave per node. Lane = (edge-slot g = lane>>4) x (feature-quad q = lane&15).
// agg[node] = rsqrt(max(in_deg,1)) * sum_{s in N(node)} xs[s]  (xs is fp16).
__global__ __launch_bounds__(256) void gather_kernel(
    const half4* __restrict__ xsh, const unsigned short* __restrict__ col,
    const int* __restrict__ roff,
    float4* __restrict__ agg4, int n) {
    int lane = threadIdx.x & 63;
    int node = (blockIdx.x * 256 + threadIdx.x) >> 6;
    if (node >= n) return;
    node = __builtin_amdgcn_readfirstlane(node);   // wave-uniform -> scalar loads

    int beg = roff[node];
    int end = roff[node + 1];
    int g = lane >> 4;   // edge sub-slot 0..3
    int q = lane & 15;   // feature quad 0..15

    float4 acc = make_float4(0.f, 0.f, 0.f, 0.f);
    int j = beg;
    for (; j + 16 <= end; j += 16) {        // 16 edges: 4 x 8B loads in flight
        int s0 = col[j + g];
        int s1 = col[j + 4 + g];
        int s2 = col[j + 8 + g];
        int s3 = col[j + 12 + g];
        half4 v0 = xsh[(long)s0 * 16 + q];
        half4 v1 = xsh[(long)s1 * 16 + q];
        half4 v2 = xsh[(long)s2 * 16 + q];
        half4 v3 = xsh[(long)s3 * 16 + q];
        acc.x += ((float)v0.x + (float)v1.x) + ((float)v2.x + (float)v3.x);
        acc.y += ((float)v0.y + (float)v1.y) + ((float)v2.y + (float)v3.y);
        acc.z += ((float)v0.z + (float)v1.z) + ((float)v2.z + (float)v3.z);
        acc.w += ((float)v0.w + (float)v1.w) + ((float)v2.w + (float)v3.w);
    }
    for (; j + 8 <= end; j += 8) {
        int s0 = col[j + g];
        int s1 = col[j + 4 + g];
        half4 v0 = xsh[(long)s0 * 16 + q];
        half4 v1 = xsh[(long)s1 * 16 + q];
        acc.x += (float)v0.x + (float)v1.x;
        acc.y += (float)v0.y + (float)v1.y;
        acc.z += (float)v0.z + (float)v1.z;
        acc.w += (float)v0.w + (float)v1.w;
    }
    for (; j < end; j += 4) {               // predicated 4-edge tail
        int jj = j + g;
        int s   = (jj < end) ? (int)col[jj] : node;   // safe dummy index
        float m = (jj < end) ? 1.f : 0.f;
        half4 v = xsh[(long)s * 16 + q];
        acc.x += (float)v.x * m;
        acc.y += (float)v.y * m;
        acc.z += (float)v.z * m;
        acc.w += (float)v.w * m;
    }

    acc.x += __shfl_down(acc.x, 32);
    acc.y += __shfl_down(acc.y, 32);
    acc.z += __shfl_down(acc.z, 32);
    acc.w += __shfl_down(acc.w, 32);
    acc.x += __shfl_down(acc.x, 16);
    acc.y += __shfl_down(acc.y, 16);
    acc.z += __shfl_down(acc.z, 16);
    acc.w += __shfl_down(acc.w, 16);

    float nd = rsqrtf((float)max(end - beg, 1));
    if (lane < 16) {
        acc.x *= nd; acc.y *= nd; acc.z *= nd; acc.w *= nd;
        agg4[(long)node * 16 + q] = acc;
    }
}

// out[r][c] = agg[r][:]@W[:,c] + x[r][:]@Wr[:,c] + (b+br)[c]
// Lane c holds W[:,c], Wr[:,c] in VGPRs (static unroll); rows staged in LDS.
#define OR 32
__global__ __launch_bounds__(256) void out_kernel(
    const float4* __restrict__ agg4, const float4* __restrict__ x4,
    const float* __restrict__ W, const float* __restrict__ b,
    const float* __restrict__ Wr, const float* __restrict__ br,
    float* __restrict__ out, int n) {
    __shared__ float4 sA[OR * 16];
    __shared__ float4 sX[OR * 16];
    int t = threadIdx.x;
    int c = t & 63;
    int base = blockIdx.x * OR;

    float4 wA[16], wR[16];
    #pragma unroll
    for (int q = 0; q < 16; ++q) {
        wA[q].x = W[(4 * q + 0) * 64 + c];
        wA[q].y = W[(4 * q + 1) * 64 + c];
        wA[q].z = W[(4 * q + 2) * 64 + c];
        wA[q].w = W[(4 * q + 3) * 64 + c];
        wR[q].x = Wr[(4 * q + 0) * 64 + c];
        wR[q].y = Wr[(4 * q + 1) * 64 + c];
        wR[q].z = Wr[(4 * q + 2) * 64 + c];
        wR[q].w = Wr[(4 * q + 3) * 64 + c];
    }

    #pragma unroll
    for (int i = 0; i < 2; ++i) {          // stage 32 rows of A and X
        int qi = t + 256 * i;              // 0..511
        int row = base + (qi >> 4);
        float4 z = make_float4(0.f, 0.f, 0.f, 0.f);
        sA[qi] = (row < n) ? agg4[(long)row * 16 + (qi & 15)] : z;
        sX[qi] = (row < n) ? x4[(long)row * 16 + (qi & 15)] : z;
    }
    __syncthreads();

    int w = t >> 6;
    float bias = b[c] + br[c];
    for (int r = w * 8; r < w * 8 + 8; ++r) {
        float a0 = 0.f, a1 = 0.f, r0 = 0.f, r1 = 0.f;
        #pragma unroll
        for (int q = 0; q < 16; q += 2) {
            float4 av0 = sA[r * 16 + q];
            float4 av1 = sA[r * 16 + q + 1];
            float4 xv0 = sX[r * 16 + q];
            float4 xv1 = sX[r * 16 + q + 1];
            a0 += av0.x * wA[q].x + av0.y * wA[q].y + av0.z * wA[q].z + av0.w * wA[q].w;
            a1 += av1.x * wA[q + 1].x + av1.y * wA[q + 1].y + av1.z * wA[q + 1].z + av1.w * wA[q + 1].w;
            r0 += xv0.x * wR[q].x + xv0.y * wR[q].y + xv0.z * wR[q].z + xv0.w * wR[q].w;
            r1 += xv1.x * wR[q + 1].x + xv1.y * wR[q + 1].y + xv1.z * wR[q + 1].z + xv1.w * wR[q + 1].w;
        }
        int grow = base + r;
        if (grow < n) out[(long)grow * 64 + c] = (a0 + a1) + (r0 + r1) + bias;
    }
}

extern "C" void kernel_launch(void* const* d_in, const int* in_sizes, int n_in,
                              void* d_out, int out_size, void* d_ws, size_t ws_size,
                              hipStream_t stream) {
    const float* x   = (const float*)d_in[0];
    const int*   src = (const int*)d_in[1];
    const int*   dst = (const int*)d_in[2];
    const float* W   = (const float*)d_in[3];
    const float* b   = (const float*)d_in[4];
    const float* Wr  = (const float*)d_in[5];
    const float* br  = (const float*)d_in[6];
    float* out = (float*)d_out;

    int n = in_sizes[0] / 64;                  // 50000
    int e = in_sizes[1];                       // 800000
    int nb = (e + TILE - 1) / TILE;            // 391 bucket tiles
    int nrange = (n + 255) / 256;              // 196 node ranges
    int m = 2 * 256 * nb;                      // 200192 hist entries
    int nbs = (m + 4095) / 4096;               // 49 scan blocks
    int grid = 2 * nrange > nb ? 2 * nrange : nb;   // 392
    if (grid < nbs) grid = nbs;

    char* p = (char*)d_ws;
    int* H      = (int*)p;  p += (size_t)m * 4;
    int* Hoff   = (int*)p;  p += (size_t)m * 4;
    int* part   = (int*)p;  p += 1024;
    int* packed = (int*)p;  p += (size_t)e * 4;
    int* roff   = (int*)p;  p += (size_t)(n + 1) * 4;
    p = (char*)(((uintptr_t)p + 15) & ~(uintptr_t)15);
    unsigned short* col = (unsigned short*)p;  p += (size_t)e * 2;
    p = (char*)(((uintptr_t)p + 15) & ~(uintptr_t)15);
    half4* xsh  = (half4*)p;  p += (size_t)n * 64 * 2;
    p = (char*)(((uintptr_t)p + 15) & ~(uintptr_t)15);
    float* agg  = (float*)p;  p += (size_t)n * 64 * 4;
    unsigned char* ksrc2 = (unsigned char*)p;   // e bytes

    const float4* x4 = (const float4*)x;
    void* kargs[] = {
        (void*)&src, (void*)&dst, (void*)&H, (void*)&part, (void*)&Hoff,
        (void*)&packed, (void*)&ksrc2, (void*)&roff, (void*)&col,
        (void*)&x4, (void*)&xsh,
        (void*)&n, (void*)&e, (void*)&nb, (void*)&nbs, (void*)&nrange
    };
    hipLaunchCooperativeKernel((void*)build_kernel, dim3(grid), dim3(256),
                               kargs, 0, stream);

    gather_kernel<<<(n * 64 + 255) / 256, 256, 0, stream>>>(
        xsh, col, roff, (float4*)agg, n);

    out_kernel<<<(n + OR - 1) / OR, 256, 0, stream>>>(
        (const float4*)agg, (const float4*)x, W, b, Wr, br, out, n);
}

// Round 15
// 104.733 us; speedup vs baseline: 3.0364x; 3.0364x over previous
//
#include <hip/hip_runtime.h>

// ---------------------------------------------------------------------------
// GraphConv (DGL norm='both') + residual linear:
//   out = (D_dst^-1/2 * A^T * (D_src^-1/2 * x)) @ W + x @ Wr + (b + br)
// Round 15: R13 structure (7 launches, zero global atomics, fp16 xs, ushort
// col) + fp16 agg (halves the agg write+read between gather and out).
// ---------------------------------------------------------------------------

#define TILE 4096   // edges per bucket block

typedef __attribute__((ext_vector_type(4))) _Float16 half4;

// Per-block LDS histograms of dst>>8 and src>>8.
// H layout: H[bin*nb + blk] (dst), H[256*nb + bin*nb + blk] (src).
__global__ __launch_bounds__(256) void bucket_hist_kernel(
    const int* __restrict__ src, const int* __restrict__ dst,
    int* __restrict__ H, int e, int nb) {
    __shared__ int hd[256], hs[256];
    int t = threadIdx.x, blk = blockIdx.x;
    hd[t] = 0; hs[t] = 0;
    __syncthreads();
    int base = blk * TILE;
    #pragma unroll
    for (int s = 0; s < 16; ++s) {
        int j = base + s * 256 + t;
        if (j < e) {
            atomicAdd(&hd[dst[j] >> 8], 1);
            atomicAdd(&hs[src[j] >> 8], 1);
        }
    }
    __syncthreads();
    H[t * nb + blk]            = hd[t];
    H[256 * nb + t * nb + blk] = hs[t];
}

// Scan phase A: 4096 elems/block partial sums.
__global__ void partial_kernel(const int* __restrict__ cnt, int* __restrict__ part, int m) {
    __shared__ int sm[256];
    int t = threadIdx.x;
    int base = blockIdx.x * 4096 + t * 16;
    int s = 0;
    if (base + 16 <= m) {
        const int4* p = (const int4*)(cnt + base);
        #pragma unroll
        for (int k = 0; k < 4; ++k) { int4 v = p[k]; s += v.x + v.y + v.z + v.w; }
    } else {
        for (int k = 0; k < 16; ++k) if (base + k < m) s += cnt[base + k];
    }
    sm[t] = s;
    __syncthreads();
    for (int st = 128; st > 0; st >>= 1) {
        if (t < st) sm[t] += sm[t + st];
        __syncthreads();
    }
    if (t == 0) part[blockIdx.x] = sm[0];
}

// Scan phase B+C fused: each block redundantly exclusive-scans the (<=256)
// partials in LDS, then does its local 4096-elem exclusive scan -> Hoff.
__global__ void scan_final_kernel(const int* __restrict__ cnt, const int* __restrict__ part,
                                  int* __restrict__ Hoff, int m, int nbs) {
    __shared__ int sm[256], sp[256];
    int t = threadIdx.x;
    int pv = (t < nbs) ? part[t] : 0;
    sp[t] = pv;
    __syncthreads();
    for (int d = 1; d < 256; d <<= 1) {
        int add = (t >= d) ? sp[t - d] : 0;
        __syncthreads();
        sp[t] += add;
        __syncthreads();
    }
    sp[t] -= pv;   // exclusive
    __syncthreads();
    int blkoff = sp[blockIdx.x];

    int base = blockIdx.x * 4096 + t * 16;
    int v[16];
    #pragma unroll
    for (int k = 0; k < 16; ++k) v[k] = (base + k < m) ? cnt[base + k] : 0;
    int s = 0;
    #pragma unroll
    for (int k = 0; k < 16; ++k) { int x = v[k]; v[k] = s; s += x; }
    sm[t] = s;
    __syncthreads();
    for (int d = 1; d < 256; d <<= 1) {
        int add = (t >= d) ? sm[t - d] : 0;
        __syncthreads();
        sm[t] += add;
        __syncthreads();
    }
    int tb = sm[t] - s + blkoff;
    #pragma unroll
    for (int k = 0; k < 16; ++k)
        if (base + k < m) Hoff[base + k] = v[k] + tb;
}

// Scatter edges into range buckets. packed = (src<<8)|(dst&255) into dst
// buckets; 1-byte (src&255) into src buckets. LDS cursors, cached stores.
__global__ __launch_bounds__(256) void bucket_scatter_kernel(
    const int* __restrict__ src, const int* __restrict__ dst,
    const int* __restrict__ Hoff,
    int* __restrict__ packed, unsigned char* __restrict__ ksrc2,
    int e, int nb) {
    __shared__ int dcur[256], scur[256];
    int t = threadIdx.x, blk = blockIdx.x;
    dcur[t] = Hoff[t * nb + blk];
    scur[t] = Hoff[256 * nb + t * nb + blk] - e;   // src offsets live in [e,2e)
    __syncthreads();
    int base = blk * TILE;
    #pragma unroll
    for (int s2 = 0; s2 < 16; ++s2) {
        int j = base + s2 * 256 + t;
        if (j < e) {
            int d = dst[j], sv = src[j];
            int pd = atomicAdd(&dcur[d >> 8], 1);
            packed[pd] = (sv << 8) | (d & 255);
            int ps = atomicAdd(&scur[sv >> 8], 1);
            ksrc2[ps] = (unsigned char)(sv & 255);
        }
    }
}

// Fused grid: blocks [0,nrange) build CSR (roff + ushort col); blocks
// [nrange,2*nrange) compute out-degree + fp16 prescale of x.
__global__ __launch_bounds__(256) void csr_outdeg_kernel(
    const int* __restrict__ packed, const unsigned char* __restrict__ ksrc2,
    const int* __restrict__ Hoff,
    int* __restrict__ roff, unsigned short* __restrict__ col,
    const float4* __restrict__ x4, half4* __restrict__ xsh,
    int n, int e, int nb, int nrange) {
    __shared__ int lh[256], sm[256];
    int t = threadIdx.x;
    int r = blockIdx.x;
    if (r < nrange) {
        // ---- CSR build for dst range r ----
        int beg = Hoff[r * nb];
        int end = (r + 1 < nrange) ? Hoff[(r + 1) * nb] : e;
        lh[t] = 0;
        __syncthreads();
        for (int j = beg + t; j < end; j += 256)
            atomicAdd(&lh[packed[j] & 255], 1);
        __syncthreads();
        int v0 = lh[t];
        sm[t] = v0;
        __syncthreads();
        for (int d = 1; d < 256; d <<= 1) {
            int add = (t >= d) ? sm[t - d] : 0;
            __syncthreads();
            sm[t] += add;
            __syncthreads();
        }
        int excl = sm[t] - v0;
        int v = r * 256 + t;
        if (v < n) roff[v] = beg + excl;
        __syncthreads();          // all v0 reads done before lh reuse
        lh[t] = excl;             // lh becomes the local cursor array
        __syncthreads();
        for (int j = beg + t; j < end; j += 256) {
            int p = packed[j];
            int pos = beg + atomicAdd(&lh[p & 255], 1);
            col[pos] = (unsigned short)(p >> 8);
        }
        if (r == 0 && t == 0) roff[n] = e;
    } else {
        // ---- out-degree + fp16 prescale for src range r-nrange ----
        r -= nrange;
        lh[t] = 0;
        __syncthreads();
        int beg = Hoff[256 * nb + r * nb] - e;
        int end = (r + 1 < nrange) ? (Hoff[256 * nb + (r + 1) * nb] - e) : e;
        for (int j = beg + t; j < end; j += 256)
            atomicAdd(&lh[ksrc2[j]], 1);
        __syncthreads();
        int base = r * 256;
        for (int i = t; i < 256 * 16; i += 256) {
            int row = i >> 4, g = base + row;
            if (g < n) {
                float s = rsqrtf((float)max(lh[row], 1));
                float4 v = x4[(long)g * 16 + (i & 15)];
                half4 h;
                h.x = (_Float16)(v.x * s);
                h.y = (_Float16)(v.y * s);
                h.z = (_Float16)(v.z * s);
                h.w = (_Float16)(v.w * s);
                xsh[(long)g * 16 + (i & 15)] = h;
            }
        }
    }
}

// One wave per node. Lane = (edge-slot g = lane>>4) x (feature-quad q = lane&15).
// agg[node] = rsqrt(max(in_deg,1)) * sum xs[s]; output in fp16.
__global__ __launch_bounds__(256) void gather_kernel(
    const half4* __restrict__ xsh, const unsigned short* __restrict__ col,
    const int* __restrict__ roff,
    half4* __restrict__ aggh, int n) {
    int lane = threadIdx.x & 63;
    int node = (blockIdx.x * 256 + threadIdx.x) >> 6;
    if (node >= n) return;
    node = __builtin_amdgcn_readfirstlane(node);   // wave-uniform -> scalar loads

    int beg = roff[node];
    int end = roff[node + 1];
    int g = lane >> 4;   // edge sub-slot 0..3
    int q = lane & 15;   // feature quad 0..15

    float4 acc = make_float4(0.f, 0.f, 0.f, 0.f);
    int j = beg;
    for (; j + 16 <= end; j += 16) {        // 16 edges: 4 x 8B loads in flight
        int s0 = col[j + g];
        int s1 = col[j + 4 + g];
        int s2 = col[j + 8 + g];
        int s3 = col[j + 12 + g];
        half4 v0 = xsh[(long)s0 * 16 + q];
        half4 v1 = xsh[(long)s1 * 16 + q];
        half4 v2 = xsh[(long)s2 * 16 + q];
        half4 v3 = xsh[(long)s3 * 16 + q];
        acc.x += ((float)v0.x + (float)v1.x) + ((float)v2.x + (float)v3.x);
        acc.y += ((float)v0.y + (float)v1.y) + ((float)v2.y + (float)v3.y);
        acc.z += ((float)v0.z + (float)v1.z) + ((float)v2.z + (float)v3.z);
        acc.w += ((float)v0.w + (float)v1.w) + ((float)v2.w + (float)v3.w);
    }
    for (; j + 8 <= end; j += 8) {
        int s0 = col[j + g];
        int s1 = col[j + 4 + g];
        half4 v0 = xsh[(long)s0 * 16 + q];
        half4 v1 = xsh[(long)s1 * 16 + q];
        acc.x += (float)v0.x + (float)v1.x;
        acc.y += (float)v0.y + (float)v1.y;
        acc.z += (float)v0.z + (float)v1.z;
        acc.w += (float)v0.w + (float)v1.w;
    }
    for (; j < end; j += 4) {               // predicated 4-edge tail
        int jj = j + g;
        int s   = (jj < end) ? (int)col[jj] : node;   // safe dummy index
        float m = (jj < end) ? 1.f : 0.f;
        half4 v = xsh[(long)s * 16 + q];
        acc.x += (float)v.x * m;
        acc.y += (float)v.y * m;
        acc.z += (float)v.z * m;
        acc.w += (float)v.w * m;
    }

    acc.x += __shfl_down(acc.x, 32);
    acc.y += __shfl_down(acc.y, 32);
    acc.z += __shfl_down(acc.z, 32);
    acc.w += __shfl_down(acc.w, 32);
    acc.x += __shfl_down(acc.x, 16);
    acc.y += __shfl_down(acc.y, 16);
    acc.z += __shfl_down(acc.z, 16);
    acc.w += __shfl_down(acc.w, 16);

    float nd = rsqrtf((float)max(end - beg, 1));
    if (lane < 16) {
        half4 h;
        h.x = (_Float16)(acc.x * nd);
        h.y = (_Float16)(acc.y * nd);
        h.z = (_Float16)(acc.z * nd);
        h.w = (_Float16)(acc.w * nd);
        aggh[(long)node * 16 + q] = h;
    }
}

// out[r][c] = agg[r][:]@W[:,c] + x[r][:]@Wr[:,c] + (b+br)[c]
// Lane c holds W[:,c], Wr[:,c] in VGPRs (static unroll); rows staged in LDS.
#define OR 32
__global__ __launch_bounds__(256) void out_kernel(
    const half4* __restrict__ aggh, const float4* __restrict__ x4,
    const float* __restrict__ W, const float* __restrict__ b,
    const float* __restrict__ Wr, const float* __restrict__ br,
    float* __restrict__ out, int n) {
    __shared__ float4 sA[OR * 16];
    __shared__ float4 sX[OR * 16];
    int t = threadIdx.x;
    int c = t & 63;
    int base = blockIdx.x * OR;

    float4 wA[16], wR[16];
    #pragma unroll
    for (int q = 0; q < 16; ++q) {
        wA[q].x = W[(4 * q + 0) * 64 + c];
        wA[q].y = W[(4 * q + 1) * 64 + c];
        wA[q].z = W[(4 * q + 2) * 64 + c];
        wA[q].w = W[(4 * q + 3) * 64 + c];
        wR[q].x = Wr[(4 * q + 0) * 64 + c];
        wR[q].y = Wr[(4 * q + 1) * 64 + c];
        wR[q].z = Wr[(4 * q + 2) * 64 + c];
        wR[q].w = Wr[(4 * q + 3) * 64 + c];
    }

    #pragma unroll
    for (int i = 0; i < 2; ++i) {          // stage 32 rows of A (fp16->f32) and X
        int qi = t + 256 * i;              // 0..511
        int row = base + (qi >> 4);
        float4 z = make_float4(0.f, 0.f, 0.f, 0.f);
        float4 a = z;
        if (row < n) {
            half4 h = aggh[(long)row * 16 + (qi & 15)];
            a.x = (float)h.x; a.y = (float)h.y; a.z = (float)h.z; a.w = (float)h.w;
        }
        sA[qi] = a;
        sX[qi] = (row < n) ? x4[(long)row * 16 + (qi & 15)] : z;
    }
    __syncthreads();

    int w = t >> 6;
    float bias = b[c] + br[c];
    for (int r = w * 8; r < w * 8 + 8; ++r) {
        float a0 = 0.f, a1 = 0.f, r0 = 0.f, r1 = 0.f;
        #pragma unroll
        for (int q = 0; q < 16; q += 2) {
            float4 av0 = sA[r * 16 + q];
            float4 av1 = sA[r * 16 + q + 1];
            float4 xv0 = sX[r * 16 + q];
            float4 xv1 = sX[r * 16 + q + 1];
            a0 += av0.x * wA[q].x + av0.y * wA[q].y + av0.z * wA[q].z + av0.w * wA[q].w;
            a1 += av1.x * wA[q + 1].x + av1.y * wA[q + 1].y + av1.z * wA[q + 1].z + av1.w * wA[q + 1].w;
            r0 += xv0.x * wR[q].x + xv0.y * wR[q].y + xv0.z * wR[q].z + xv0.w * wR[q].w;
            r1 += xv1.x * wR[q + 1].x + xv1.y * wR[q + 1].y + xv1.z * wR[q + 1].z + xv1.w * wR[q + 1].w;
        }
        int grow = base + r;
        if (grow < n) out[(long)grow * 64 + c] = (a0 + a1) + (r0 + r1) + bias;
    }
}

extern "C" void kernel_launch(void* const* d_in, const int* in_sizes, int n_in,
                              void* d_out, int out_size, void* d_ws, size_t ws_size,
                              hipStream_t stream) {
    const float* x   = (const float*)d_in[0];
    const int*   src = (const int*)d_in[1];
    const int*   dst = (const int*)d_in[2];
    const float* W   = (const float*)d_in[3];
    const float* b   = (const float*)d_in[4];
    const float* Wr  = (const float*)d_in[5];
    const float* br  = (const float*)d_in[6];
    float* out = (float*)d_out;

    const int n = in_sizes[0] / 64;            // 50000
    const int e = in_sizes[1];                 // 800000
    const int nb = (e + TILE - 1) / TILE;      // 196 bucket blocks
    const int nrange = (n + 255) / 256;        // 196 node ranges
    const int m = 2 * 256 * nb;                // 100352 hist entries
    const int nbs = (m + 4095) / 4096;         // 25 scan blocks

    char* p = (char*)d_ws;
    int* H      = (int*)p;  p += (size_t)m * 4;
    int* Hoff   = (int*)p;  p += (size_t)m * 4;
    int* part   = (int*)p;  p += 1024;
    int* packed = (int*)p;  p += (size_t)e * 4;
    int* roff   = (int*)p;  p += (size_t)(n + 1) * 4;
    p = (char*)(((uintptr_t)p + 15) & ~(uintptr_t)15);
    unsigned short* col = (unsigned short*)p;  p += (size_t)e * 2;
    p = (char*)(((uintptr_t)p + 15) & ~(uintptr_t)15);
    half4* xsh  = (half4*)p;  p += (size_t)n * 64 * 2;
    p = (char*)(((uintptr_t)p + 15) & ~(uintptr_t)15);
    half4* aggh = (half4*)p;  p += (size_t)n * 64 * 2;
    unsigned char* ksrc2 = (unsigned char*)p;   // e bytes

    bucket_hist_kernel<<<nb, 256, 0, stream>>>(src, dst, H, e, nb);

    partial_kernel<<<nbs, 256, 0, stream>>>(H, part, m);
    scan_final_kernel<<<nbs, 256, 0, stream>>>(H, part, Hoff, m, nbs);

    bucket_scatter_kernel<<<nb, 256, 0, stream>>>(src, dst, Hoff, packed, ksrc2, e, nb);

    csr_outdeg_kernel<<<2 * nrange, 256, 0, stream>>>(
        packed, ksrc2, Hoff, roff, col, (const float4*)x, xsh, n, e, nb, nrange);

    gather_kernel<<<(n * 64 + 255) / 256, 256, 0, stream>>>(
        xsh, col, roff, aggh, n);

    out_kernel<<<(n + OR - 1) / OR, 256, 0, stream>>>(
        aggh, (const float4*)x, W, b, Wr, br, out, n);
}